// Round 15
// baseline (100.514 us; speedup 1.0000x reference)
//
#include <hip/hip_runtime.h>

typedef __attribute__((ext_vector_type(8))) short short8;
typedef __bf16 bf16x8 __attribute__((ext_vector_type(8)));
typedef __attribute__((ext_vector_type(4))) float f32x4;

static constexpr int Cn = 256, Nn = 2048;
static constexpr float EPSf = 1e-5f;
static constexpr float LOG2E = 1.44269504088896f;

#define DEV __device__ __forceinline__

DEV unsigned short f2bf(float f) { return __builtin_bit_cast(unsigned short, (__bf16)f); }
DEV float bf2f(unsigned u16) { return __builtin_bit_cast(float, u16 << 16); }
DEV unsigned pk2bf(float a, float b) {
  return (unsigned)f2bf(a) | ((unsigned)f2bf(b) << 16);
}
DEV f32x4 mfma16(short8 a, short8 b, f32x4 c) {
  return __builtin_amdgcn_mfma_f32_16x16x32_bf16(
      __builtin_bit_cast(bf16x8, a), __builtin_bit_cast(bf16x8, b), c, 0, 0, 0);
}
DEV short8 ld8(const unsigned short* p) { return *(const short8*)p; }

// ---------------- K1: fused convert+transpose+channel-mix GEMMs (r11) ---------
__global__ __launch_bounds__(256) void k_mix(
    const float* __restrict__ x, const float* __restrict__ y,
    const float* __restrict__ Wp, const float* __restrict__ Wt,
    const float* __restrict__ Wg, unsigned short* __restrict__ P,
    unsigned short* __restrict__ T, unsigned short* __restrict__ Gt,
    float* __restrict__ SUMS) {
  __shared__ __align__(16) unsigned short lds[12800];  // A[256][40] | B[64][40]

  int t = threadIdx.x, lane = t & 63, w = t >> 6;
  int q = lane >> 4, li = lane & 15;
  int zb = blockIdx.y, b = zb & 3, op = zb >> 2;
  const float* in = (op == 0 ? x : y) + (size_t)b * Cn * Nn;
  const float* W = (op == 0 ? Wp : (op == 1 ? Wt : Wg));
  int h0 = blockIdx.x * 64;
  if (blockIdx.x == 0 && zb == 0 && t < 32) SUMS[t] = 0.f;

  int arow = t >> 3, ac4 = t & 7;   // A: 32 rows x 8 f4-cols, x8 row-groups
  int bcp = t >> 4, bh4 = t & 15;   // B: c-pair, h-quad
  float4 wv[8], bv0, bv1;
#pragma unroll
  for (int i2 = 0; i2 < 8; ++i2)
    wv[i2] = *(const float4*)&W[(size_t)(i2 * 32 + arow) * 256 + ac4 * 4];
  bv0 = *(const float4*)&in[(size_t)(2 * bcp) * Nn + h0 + bh4 * 4];
  bv1 = *(const float4*)&in[(size_t)(2 * bcp + 1) * Nn + h0 + bh4 * 4];

  unsigned* bdst = (unsigned*)&lds[10240];  // dword view: [h][c/2], 20 dw/row
  f32x4 acc[4][4] = {};
  for (int kk = 0; kk < 8; ++kk) {
    __syncthreads();
#pragma unroll
    for (int i2 = 0; i2 < 8; ++i2)
      *(uint2*)&lds[(i2 * 32 + arow) * 40 + ac4 * 4] =
          make_uint2(pk2bf(wv[i2].x, wv[i2].y), pk2bf(wv[i2].z, wv[i2].w));
    {
      int hL = bh4 * 4;
      bdst[(hL + 0) * 20 + bcp] = pk2bf(bv0.x, bv1.x);
      bdst[(hL + 1) * 20 + bcp] = pk2bf(bv0.y, bv1.y);
      bdst[(hL + 2) * 20 + bcp] = pk2bf(bv0.z, bv1.z);
      bdst[(hL + 3) * 20 + bcp] = pk2bf(bv0.w, bv1.w);
    }
    if (kk < 7) {
      int k1 = (kk + 1) * 32;
#pragma unroll
      for (int i2 = 0; i2 < 8; ++i2)
        wv[i2] = *(const float4*)&W[(size_t)(i2 * 32 + arow) * 256 + k1 + ac4 * 4];
      bv0 = *(const float4*)&in[(size_t)(k1 + 2 * bcp) * Nn + h0 + bh4 * 4];
      bv1 = *(const float4*)&in[(size_t)(k1 + 2 * bcp + 1) * Nn + h0 + bh4 * 4];
    }
    __syncthreads();
    int pw = w * 64;
    short8 af[4];
#pragma unroll
    for (int mt = 0; mt < 4; ++mt)
      af[mt] = *(const short8*)&lds[(pw + mt * 16 + li) * 40 + q * 8];
#pragma unroll
    for (int nt = 0; nt < 4; ++nt) {
      short8 bfr = *(const short8*)&lds[10240 + (nt * 16 + li) * 40 + q * 8];
#pragma unroll
      for (int mt = 0; mt < 4; ++mt) acc[mt][nt] = mfma16(af[mt], bfr, acc[mt][nt]);
    }
  }
  int pw = w * 64;
  if (op < 2) {
    unsigned short* dst = (op == 0 ? P : T) + (size_t)b * Cn * Nn;
#pragma unroll
    for (int mt = 0; mt < 4; ++mt)
#pragma unroll
      for (int nt = 0; nt < 4; ++nt)
#pragma unroll
        for (int r = 0; r < 4; ++r)
          dst[(size_t)(pw + mt * 16 + q * 4 + r) * Nn + h0 + nt * 16 + li] =
              f2bf(acc[mt][nt][r]);
  } else {
#pragma unroll
    for (int mt = 0; mt < 4; ++mt)
#pragma unroll
      for (int nt = 0; nt < 4; ++nt)
#pragma unroll
        for (int r = 0; r < 4; ++r) {
          int c = pw + mt * 16 + q * 4 + r;
          int h = h0 + nt * 16 + li;
          Gt[(((size_t)(b * 4 + (c >> 6)) * Nn + h) << 6) + (c & 63)] =
              f2bf(acc[mt][nt][r] * LOG2E);
        }
  }
}

// ---------------- K3: attention (r11 verbatim — verified 42us) ----------------
__global__ __launch_bounds__(256) void k_attn(
    const unsigned short* __restrict__ Pq, const unsigned short* __restrict__ Tv,
    const unsigned short* __restrict__ Gt, unsigned short* __restrict__ OT) {
  __shared__ __align__(16) unsigned short lds[16384];  // K dbuf 2x8KB | V dbuf 2x8KB

  int t = threadIdx.x, lane = t & 63, w = t >> 6;
  int q = lane >> 4, li = lane & 15;
  int bid = blockIdx.x;
  int xcd = bid & 7, slot = bid >> 3;        // 64 slots per XCD
  int bg = xcd * 2 + (slot >> 5);            // 2 heads per XCD (L2-resident)
  int i0 = (slot & 31) * 64;
  int b = bg >> 2, g = bg & 3;
  const unsigned short* Q = Pq + (size_t)(b * Cn + g * 64) * Nn;
  const unsigned short* V = Tv + (size_t)(b * Cn + g * 64) * Nn;
  const unsigned short* Kk = Gt + (size_t)bg * Nn * 64;

  int iw = i0 + w * 16;  // this wave's 16 q-rows
  short8 qf[2];
#pragma unroll
  for (int cs = 0; cs < 2; ++cs) {
    short8 v;
#pragma unroll
    for (int e = 0; e < 8; ++e)
      v[e] = (short)Q[(size_t)(cs * 32 + q * 8 + e) * Nn + iw + li];
    qf[cs] = v;
  }
  f32x4 O[4] = {};
  float rs = 0.f;

  // ---- hoisted LDS addresses (ushort units) ----
  int swz = li & 7;
  int rb0 = li * 64 + ((q ^ swz) << 3);
  int rb1 = li * 64 + (((4 + q) ^ swz) << 3);
  int srow = t >> 2, sq = t & 3;
  int wk0 = srow * 64 + ((sq ^ (srow & 7)) << 3);
  int wk1 = srow * 64 + (((sq + 4) ^ (srow & 7)) << 3);

  // ---- running global staging pointers (advance by const per tile) ----
  const unsigned short* kp0 = Kk + srow * 64 + sq * 8;
  const unsigned short* kp1 = kp0 + 32;
  const unsigned short* vp0 = V + (size_t)srow * Nn + sq * 8;
  const unsigned short* vp1 = vp0 + 32;

  short8 kst[2], vst[2];
  kst[0] = ld8(kp0); kst[1] = ld8(kp1);
  vst[0] = ld8(vp0); vst[1] = ld8(vp1);
  kp0 += 4096; kp1 += 4096; vp0 += 64; vp1 += 64;

  auto load_next = [&]() {
    kst[0] = ld8(kp0); kst[1] = ld8(kp1);
    vst[0] = ld8(vp0); vst[1] = ld8(vp1);
    kp0 += 4096; kp1 += 4096; vp0 += 64; vp1 += 64;
  };

  auto stage = [&](int KB) {  // KB literal: 0 or 4096
    *(short8*)&lds[KB + wk0] = kst[0];
    *(short8*)&lds[KB + wk1] = kst[1];
    *(short8*)&lds[KB + 8192 + wk0] = vst[0];
    *(short8*)&lds[KB + 8192 + wk1] = vst[1];
  };

  auto compute = [&](int KB) {  // KB literal: 0 or 4096
    f32x4 F[4] = {};
#pragma unroll
    for (int jt = 0; jt < 4; ++jt) {
      short8 k0 = *(const short8*)&lds[KB + jt * 1024 + rb0];
      short8 k1 = *(const short8*)&lds[KB + jt * 1024 + rb1];
      F[jt] = mfma16(k0, qf[0], F[jt]);
      F[jt] = mfma16(k1, qf[1], F[jt]);
    }
    unsigned pa[4], pb[4];
#pragma unroll
    for (int jt = 0; jt < 4; ++jt) {
      float e0 = __builtin_amdgcn_exp2f(F[jt][0]);
      float e1 = __builtin_amdgcn_exp2f(F[jt][1]);
      float e2 = __builtin_amdgcn_exp2f(F[jt][2]);
      float e3 = __builtin_amdgcn_exp2f(F[jt][3]);
      rs += (e0 + e1) + (e2 + e3);
      pa[jt] = pk2bf(e0, e1);
      pb[jt] = pk2bf(e2, e3);
    }
#pragma unroll
    for (int cs = 0; cs < 2; ++cs) {
      unsigned a0 = pa[2 * cs], a1 = pa[2 * cs + 1];
      unsigned b0 = pb[2 * cs], b1 = pb[2 * cs + 1];
      asm("v_permlane32_swap_b32 %0, %1" : "+v"(a0), "+v"(a1));
      asm("v_permlane16_swap_b32 %0, %1" : "+v"(a0), "+v"(a1));
      asm("v_permlane32_swap_b32 %0, %1" : "+v"(b0), "+v"(b1));
      asm("v_permlane16_swap_b32 %0, %1" : "+v"(b0), "+v"(b1));
      int4 fi = make_int4((int)a0, (int)b0, (int)a1, (int)b1);
      short8 pf = __builtin_bit_cast(short8, fi);
      int rbv = cs ? rb1 : rb0;
#pragma unroll
      for (int ct = 0; ct < 4; ++ct) {
        short8 vf = *(const short8*)&lds[KB + 8192 + ct * 1024 + rbv];
        O[ct] = mfma16(pf, vf, O[ct]);
      }
    }
  };

  for (int tp = 0; tp < 16; ++tp) {
    __syncthreads();
    stage(0);
    load_next();                       // tile 2tp+1
    if (tp > 0) compute(4096);         // tile 2tp-1
    __syncthreads();
    stage(4096);
    if (tp < 15) load_next();          // tile 2tp+2
    compute(0);                        // tile 2tp
  }
  __syncthreads();
  compute(4096);                       // tile 31

  rs += __shfl_xor(rs, 16);
  rs += __shfl_xor(rs, 32);
  float r0 = 1.f / __shfl(rs, q * 4 + 0);
  float r1 = 1.f / __shfl(rs, q * 4 + 1);
  float r2 = 1.f / __shfl(rs, q * 4 + 2);
  float r3 = 1.f / __shfl(rs, q * 4 + 3);
  unsigned short* op = OT + (size_t)bg * Nn * 64;
#pragma unroll
  for (int ct = 0; ct < 4; ++ct) {
    op[(size_t)(iw + q * 4 + 0) * 64 + ct * 16 + li] = f2bf(O[ct][0] * r0);
    op[(size_t)(iw + q * 4 + 1) * 64 + ct * 16 + li] = f2bf(O[ct][1] * r1);
    op[(size_t)(iw + q * 4 + 2) * 64 + ct * 16 + li] = f2bf(O[ct][2] * r2);
    op[(size_t)(iw + q * 4 + 3) * 64 + ct * 16 + li] = f2bf(O[ct][3] * r3);
  }
}

// ---------------- K4: grouped conv + sum/sumsq — 64-row blocks (2/CU) ---------
// Same math as r11's k_zconv; i-tile halved to 64 rows, grid (32,16)=512 blocks
// so two blocks co-reside per CU and overlap each other's barrier/latency.
__global__ __launch_bounds__(256) void k_zconv(
    const float* __restrict__ Wz, const unsigned short* __restrict__ OT,
    unsigned short* __restrict__ Zb, float* __restrict__ SUMS) {
  __shared__ __align__(16) unsigned short lds[8192];  // m[64][64] | Wzs[64][64]
  int t = threadIdx.x, lane = t & 63, w = t >> 6;
  int q = lane >> 4, li = lane & 15;
  int bg = blockIdx.y, b = bg >> 2, g = bg & 3;
  int i0 = blockIdx.x * 64;
  const unsigned short* region = OT + ((size_t)bg * Nn + i0) * 64;
#pragma unroll
  for (int p = 0; p < 2; ++p) {
    int chunk = p * 256 + t;
    int row = chunk >> 3, sl = chunk & 7;
    short8 v = ld8(region + row * 64 + sl * 8);
    *(short8*)&lds[row * 64 + (sl ^ (row & 7)) * 8] = v;
  }
  const float* Wg2 = Wz + g * 64 * 64;
#pragma unroll
  for (int p = 0; p < 4; ++p) {
    int o = p * 16 + (t >> 4), f4c = t & 15;
    float4 v = *(const float4*)&Wg2[o * 64 + f4c * 4];
    *(uint2*)&lds[4096 + o * 64 + ((f4c >> 1) ^ (o & 7)) * 8 + (f4c & 1) * 4] =
        make_uint2(pk2bf(v.x, v.y), pk2bf(v.z, v.w));
  }
  __syncthreads();
  f32x4 acc[4] = {};
#pragma unroll
  for (int cs = 0; cs < 2; ++cs) {
    int hrow = w * 16 + li;
    short8 bfr = *(const short8*)&lds[hrow * 64 + ((cs * 4 + q) ^ (hrow & 7)) * 8];
#pragma unroll
    for (int mt = 0; mt < 4; ++mt) {
      int orow = mt * 16 + li;
      short8 af =
          *(const short8*)&lds[4096 + orow * 64 + ((cs * 4 + q) ^ (orow & 7)) * 8];
      acc[mt] = mfma16(af, bfr, acc[mt]);
    }
  }
  float s1 = 0.f, s2 = 0.f;
  unsigned short* zb = Zb + (size_t)(b * Cn + g * 64) * Nn;
#pragma unroll
  for (int mt = 0; mt < 4; ++mt)
#pragma unroll
    for (int r = 0; r < 4; ++r) {
      float v = acc[mt][r];
      s1 += v; s2 += v * v;
      zb[(size_t)(mt * 16 + q * 4 + r) * Nn + i0 + w * 16 + li] = f2bf(v);
    }
#pragma unroll
  for (int off = 32; off; off >>= 1) {
    s1 += __shfl_xor(s1, off);
    s2 += __shfl_xor(s2, off);
  }
  if (lane == 0) {
    atomicAdd(&SUMS[bg * 2], s1);
    atomicAdd(&SUMS[bg * 2 + 1], s2);
  }
}

// ---------------- K5: GroupNorm + affine + residual (r8) ----------------------
__global__ __launch_bounds__(256) void k_norm(
    const unsigned short* __restrict__ Zb, const float* __restrict__ x,
    const float* __restrict__ gamma, const float* __restrict__ beta,
    const float* __restrict__ SUMS, float* __restrict__ out) {
  int idx = blockIdx.x * 256 + threadIdx.x;
  size_t f = (size_t)idx * 4;
  int c = (int)((f >> 11) & (Cn - 1));
  int b = (int)(f >> 19);
  int bg = b * 4 + (c >> 6);
  const float inv = 1.f / 131072.f;
  float mean = SUMS[bg * 2] * inv;
  float var = SUMS[bg * 2 + 1] * inv - mean * mean;
  float rstd = rsqrtf(var + EPSf);
  float ga = gamma[c] * rstd;
  float be = beta[c] - mean * ga;
  uint2 u = *(const uint2*)&Zb[f];
  float4 xv = *(const float4*)(x + f);
  float4 o;
  o.x = bf2f(u.x & 0xffffu) * ga + be + xv.x;
  o.y = bf2f(u.x >> 16) * ga + be + xv.y;
  o.z = bf2f(u.y & 0xffffu) * ga + be + xv.z;
  o.w = bf2f(u.y >> 16) * ga + be + xv.w;
  *(float4*)(out + f) = o;
}

extern "C" void kernel_launch(void* const* d_in, const int* in_sizes, int n_in,
                              void* d_out, int out_size, void* d_ws, size_t ws_size,
                              hipStream_t stream) {
  (void)in_sizes; (void)n_in; (void)out_size; (void)ws_size;
  const float* x = (const float*)d_in[0];
  const float* y = (const float*)d_in[1];
  const float* Wt = (const float*)d_in[2];
  const float* Wp = (const float*)d_in[3];
  const float* Wg = (const float*)d_in[4];
  const float* Wz = (const float*)d_in[5];
  const float* gamma = (const float*)d_in[6];
  const float* beta = (const float*)d_in[7];
  float* out = (float*)d_out;
  char* ws = (char*)d_ws;
  unsigned short* Pq = (unsigned short*)(ws + 0);
  unsigned short* Tv = (unsigned short*)(ws + 4194304);
  unsigned short* Gt = (unsigned short*)(ws + 8388608);
  unsigned short* OT = (unsigned short*)(ws + 12582912);
  unsigned short* Zb = (unsigned short*)(ws + 16777216);
  float* SUMS = (float*)(ws + 20971520);

  k_mix<<<dim3(32, 12), 256, 0, stream>>>(x, y, Wp, Wt, Wg, Pq, Tv, Gt, SUMS);
  k_attn<<<512, 256, 0, stream>>>(Pq, Tv, Gt, OT);
  k_zconv<<<dim3(32, 16), 256, 0, stream>>>(Wz, OT, Zb, SUMS);
  k_norm<<<2048, 256, 0, stream>>>(Zb, x, gamma, beta, SUMS, out);
}

// Round 16
// 59.481 us; speedup vs baseline: 1.6899x; 1.6899x over previous
//
#include <hip/hip_runtime.h>

typedef __attribute__((ext_vector_type(8))) short short8;
typedef __bf16 bf16x8 __attribute__((ext_vector_type(8)));
typedef __attribute__((ext_vector_type(4))) float f32x4;

static constexpr int Cn = 256, Nn = 2048;
static constexpr float EPSf = 1e-5f;
static constexpr float LOG2E = 1.44269504088896f;

#define DEV __device__ __forceinline__

DEV unsigned short f2bf(float f) { return __builtin_bit_cast(unsigned short, (__bf16)f); }
DEV float bf2f(unsigned u16) { return __builtin_bit_cast(float, u16 << 16); }
DEV unsigned pk2bf(float a, float b) {
  return (unsigned)f2bf(a) | ((unsigned)f2bf(b) << 16);
}
DEV f32x4 mfma16(short8 a, short8 b, f32x4 c) {
  return __builtin_amdgcn_mfma_f32_16x16x32_bf16(
      __builtin_bit_cast(bf16x8, a), __builtin_bit_cast(bf16x8, b), c, 0, 0, 0);
}
DEV short8 ld8(const unsigned short* p) { return *(const short8*)p; }

// ---------------- K1: fused convert+transpose+channel-mix GEMMs (r11) ---------
__global__ __launch_bounds__(256) void k_mix(
    const float* __restrict__ x, const float* __restrict__ y,
    const float* __restrict__ Wp, const float* __restrict__ Wt,
    const float* __restrict__ Wg, unsigned short* __restrict__ P,
    unsigned short* __restrict__ T, unsigned short* __restrict__ Gt,
    float* __restrict__ SUMS) {
  __shared__ __align__(16) unsigned short lds[12800];  // A[256][40] | B[64][40]

  int t = threadIdx.x, lane = t & 63, w = t >> 6;
  int q = lane >> 4, li = lane & 15;
  int zb = blockIdx.y, b = zb & 3, op = zb >> 2;
  const float* in = (op == 0 ? x : y) + (size_t)b * Cn * Nn;
  const float* W = (op == 0 ? Wp : (op == 1 ? Wt : Wg));
  int h0 = blockIdx.x * 64;
  if (blockIdx.x == 0 && zb == 0) {  // zero padded SUMS: 16 bg x 32 floats
    SUMS[t] = 0.f;
    SUMS[256 + t] = 0.f;
  }

  int arow = t >> 3, ac4 = t & 7;   // A: 32 rows x 8 f4-cols, x8 row-groups
  int bcp = t >> 4, bh4 = t & 15;   // B: c-pair, h-quad
  float4 wv[8], bv0, bv1;
#pragma unroll
  for (int i2 = 0; i2 < 8; ++i2)
    wv[i2] = *(const float4*)&W[(size_t)(i2 * 32 + arow) * 256 + ac4 * 4];
  bv0 = *(const float4*)&in[(size_t)(2 * bcp) * Nn + h0 + bh4 * 4];
  bv1 = *(const float4*)&in[(size_t)(2 * bcp + 1) * Nn + h0 + bh4 * 4];

  unsigned* bdst = (unsigned*)&lds[10240];  // dword view: [h][c/2], 20 dw/row
  f32x4 acc[4][4] = {};
  for (int kk = 0; kk < 8; ++kk) {
    __syncthreads();
#pragma unroll
    for (int i2 = 0; i2 < 8; ++i2)
      *(uint2*)&lds[(i2 * 32 + arow) * 40 + ac4 * 4] =
          make_uint2(pk2bf(wv[i2].x, wv[i2].y), pk2bf(wv[i2].z, wv[i2].w));
    {
      int hL = bh4 * 4;
      bdst[(hL + 0) * 20 + bcp] = pk2bf(bv0.x, bv1.x);
      bdst[(hL + 1) * 20 + bcp] = pk2bf(bv0.y, bv1.y);
      bdst[(hL + 2) * 20 + bcp] = pk2bf(bv0.z, bv1.z);
      bdst[(hL + 3) * 20 + bcp] = pk2bf(bv0.w, bv1.w);
    }
    if (kk < 7) {
      int k1 = (kk + 1) * 32;
#pragma unroll
      for (int i2 = 0; i2 < 8; ++i2)
        wv[i2] = *(const float4*)&W[(size_t)(i2 * 32 + arow) * 256 + k1 + ac4 * 4];
      bv0 = *(const float4*)&in[(size_t)(k1 + 2 * bcp) * Nn + h0 + bh4 * 4];
      bv1 = *(const float4*)&in[(size_t)(k1 + 2 * bcp + 1) * Nn + h0 + bh4 * 4];
    }
    __syncthreads();
    int pw = w * 64;
    short8 af[4];
#pragma unroll
    for (int mt = 0; mt < 4; ++mt)
      af[mt] = *(const short8*)&lds[(pw + mt * 16 + li) * 40 + q * 8];
#pragma unroll
    for (int nt = 0; nt < 4; ++nt) {
      short8 bfr = *(const short8*)&lds[10240 + (nt * 16 + li) * 40 + q * 8];
#pragma unroll
      for (int mt = 0; mt < 4; ++mt) acc[mt][nt] = mfma16(af[mt], bfr, acc[mt][nt]);
    }
  }
  int pw = w * 64;
  if (op < 2) {
    unsigned short* dst = (op == 0 ? P : T) + (size_t)b * Cn * Nn;
#pragma unroll
    for (int mt = 0; mt < 4; ++mt)
#pragma unroll
      for (int nt = 0; nt < 4; ++nt)
#pragma unroll
        for (int r = 0; r < 4; ++r)
          dst[(size_t)(pw + mt * 16 + q * 4 + r) * Nn + h0 + nt * 16 + li] =
              f2bf(acc[mt][nt][r]);
  } else {
#pragma unroll
    for (int mt = 0; mt < 4; ++mt)
#pragma unroll
      for (int nt = 0; nt < 4; ++nt)
#pragma unroll
        for (int r = 0; r < 4; ++r) {
          int c = pw + mt * 16 + q * 4 + r;
          int h = h0 + nt * 16 + li;
          Gt[(((size_t)(b * 4 + (c >> 6)) * Nn + h) << 6) + (c & 63)] =
              f2bf(acc[mt][nt][r] * LOG2E);
        }
  }
}

// ---------------- K3: attention (r11 verbatim — verified) ---------------------
__global__ __launch_bounds__(256) void k_attn(
    const unsigned short* __restrict__ Pq, const unsigned short* __restrict__ Tv,
    const unsigned short* __restrict__ Gt, unsigned short* __restrict__ OT) {
  __shared__ __align__(16) unsigned short lds[16384];  // K dbuf 2x8KB | V dbuf 2x8KB

  int t = threadIdx.x, lane = t & 63, w = t >> 6;
  int q = lane >> 4, li = lane & 15;
  int bid = blockIdx.x;
  int xcd = bid & 7, slot = bid >> 3;        // 64 slots per XCD
  int bg = xcd * 2 + (slot >> 5);            // 2 heads per XCD (L2-resident)
  int i0 = (slot & 31) * 64;
  int b = bg >> 2, g = bg & 3;
  const unsigned short* Q = Pq + (size_t)(b * Cn + g * 64) * Nn;
  const unsigned short* V = Tv + (size_t)(b * Cn + g * 64) * Nn;
  const unsigned short* Kk = Gt + (size_t)bg * Nn * 64;

  int iw = i0 + w * 16;  // this wave's 16 q-rows
  short8 qf[2];
#pragma unroll
  for (int cs = 0; cs < 2; ++cs) {
    short8 v;
#pragma unroll
    for (int e = 0; e < 8; ++e)
      v[e] = (short)Q[(size_t)(cs * 32 + q * 8 + e) * Nn + iw + li];
    qf[cs] = v;
  }
  f32x4 O[4] = {};
  float rs = 0.f;

  // ---- hoisted LDS addresses (ushort units) ----
  int swz = li & 7;
  int rb0 = li * 64 + ((q ^ swz) << 3);
  int rb1 = li * 64 + (((4 + q) ^ swz) << 3);
  int srow = t >> 2, sq = t & 3;
  int wk0 = srow * 64 + ((sq ^ (srow & 7)) << 3);
  int wk1 = srow * 64 + (((sq + 4) ^ (srow & 7)) << 3);

  // ---- running global staging pointers (advance by const per tile) ----
  const unsigned short* kp0 = Kk + srow * 64 + sq * 8;
  const unsigned short* kp1 = kp0 + 32;
  const unsigned short* vp0 = V + (size_t)srow * Nn + sq * 8;
  const unsigned short* vp1 = vp0 + 32;

  short8 kst[2], vst[2];
  kst[0] = ld8(kp0); kst[1] = ld8(kp1);
  vst[0] = ld8(vp0); vst[1] = ld8(vp1);
  kp0 += 4096; kp1 += 4096; vp0 += 64; vp1 += 64;

  auto load_next = [&]() {
    kst[0] = ld8(kp0); kst[1] = ld8(kp1);
    vst[0] = ld8(vp0); vst[1] = ld8(vp1);
    kp0 += 4096; kp1 += 4096; vp0 += 64; vp1 += 64;
  };

  auto stage = [&](int KB) {  // KB literal: 0 or 4096
    *(short8*)&lds[KB + wk0] = kst[0];
    *(short8*)&lds[KB + wk1] = kst[1];
    *(short8*)&lds[KB + 8192 + wk0] = vst[0];
    *(short8*)&lds[KB + 8192 + wk1] = vst[1];
  };

  auto compute = [&](int KB) {  // KB literal: 0 or 4096
    f32x4 F[4] = {};
#pragma unroll
    for (int jt = 0; jt < 4; ++jt) {
      short8 k0 = *(const short8*)&lds[KB + jt * 1024 + rb0];
      short8 k1 = *(const short8*)&lds[KB + jt * 1024 + rb1];
      F[jt] = mfma16(k0, qf[0], F[jt]);
      F[jt] = mfma16(k1, qf[1], F[jt]);
    }
    unsigned pa[4], pb[4];
#pragma unroll
    for (int jt = 0; jt < 4; ++jt) {
      float e0 = __builtin_amdgcn_exp2f(F[jt][0]);
      float e1 = __builtin_amdgcn_exp2f(F[jt][1]);
      float e2 = __builtin_amdgcn_exp2f(F[jt][2]);
      float e3 = __builtin_amdgcn_exp2f(F[jt][3]);
      rs += (e0 + e1) + (e2 + e3);
      pa[jt] = pk2bf(e0, e1);
      pb[jt] = pk2bf(e2, e3);
    }
#pragma unroll
    for (int cs = 0; cs < 2; ++cs) {
      unsigned a0 = pa[2 * cs], a1 = pa[2 * cs + 1];
      unsigned b0 = pb[2 * cs], b1 = pb[2 * cs + 1];
      asm("v_permlane32_swap_b32 %0, %1" : "+v"(a0), "+v"(a1));
      asm("v_permlane16_swap_b32 %0, %1" : "+v"(a0), "+v"(a1));
      asm("v_permlane32_swap_b32 %0, %1" : "+v"(b0), "+v"(b1));
      asm("v_permlane16_swap_b32 %0, %1" : "+v"(b0), "+v"(b1));
      int4 fi = make_int4((int)a0, (int)b0, (int)a1, (int)b1);
      short8 pf = __builtin_bit_cast(short8, fi);
      int rbv = cs ? rb1 : rb0;
#pragma unroll
      for (int ct = 0; ct < 4; ++ct) {
        short8 vf = *(const short8*)&lds[KB + 8192 + ct * 1024 + rbv];
        O[ct] = mfma16(pf, vf, O[ct]);
      }
    }
  };

  for (int tp = 0; tp < 16; ++tp) {
    __syncthreads();
    stage(0);
    load_next();                       // tile 2tp+1
    if (tp > 0) compute(4096);         // tile 2tp-1
    __syncthreads();
    stage(4096);
    if (tp < 15) load_next();          // tile 2tp+2
    compute(0);                        // tile 2tp
  }
  __syncthreads();
  compute(4096);                       // tile 31

  rs += __shfl_xor(rs, 16);
  rs += __shfl_xor(rs, 32);
  float r0 = 1.f / __shfl(rs, q * 4 + 0);
  float r1 = 1.f / __shfl(rs, q * 4 + 1);
  float r2 = 1.f / __shfl(rs, q * 4 + 2);
  float r3 = 1.f / __shfl(rs, q * 4 + 3);
  unsigned short* op = OT + (size_t)bg * Nn * 64;
#pragma unroll
  for (int ct = 0; ct < 4; ++ct) {
    op[(size_t)(iw + q * 4 + 0) * 64 + ct * 16 + li] = f2bf(O[ct][0] * r0);
    op[(size_t)(iw + q * 4 + 1) * 64 + ct * 16 + li] = f2bf(O[ct][1] * r1);
    op[(size_t)(iw + q * 4 + 2) * 64 + ct * 16 + li] = f2bf(O[ct][2] * r2);
    op[(size_t)(iw + q * 4 + 3) * 64 + ct * 16 + li] = f2bf(O[ct][3] * r3);
  }
}

// ---------------- K4: grouped conv + sum/sumsq — atomic-fixed -----------------
// r15 structure (64-row blocks, 2/CU) with the atomic storm removed:
// block-level pre-reduction (LDS) then ONE thread issues 2 atomicAdds into a
// PER-BG 128-B-padded slot (SUMS[bg*32]). 4096 same-line atomics -> 1024
// spread over 16 cache lines.
__global__ __launch_bounds__(256) void k_zconv(
    const float* __restrict__ Wz, const unsigned short* __restrict__ OT,
    unsigned short* __restrict__ Zb, float* __restrict__ SUMS) {
  __shared__ __align__(16) unsigned short lds[8192];  // m[64][64] | Wzs[64][64]
  __shared__ float red[8];
  int t = threadIdx.x, lane = t & 63, w = t >> 6;
  int q = lane >> 4, li = lane & 15;
  int bg = blockIdx.y, b = bg >> 2, g = bg & 3;
  int i0 = blockIdx.x * 64;
  const unsigned short* region = OT + ((size_t)bg * Nn + i0) * 64;
#pragma unroll
  for (int p = 0; p < 2; ++p) {
    int chunk = p * 256 + t;
    int row = chunk >> 3, sl = chunk & 7;
    short8 v = ld8(region + row * 64 + sl * 8);
    *(short8*)&lds[row * 64 + (sl ^ (row & 7)) * 8] = v;
  }
  const float* Wg2 = Wz + g * 64 * 64;
#pragma unroll
  for (int p = 0; p < 4; ++p) {
    int o = p * 16 + (t >> 4), f4c = t & 15;
    float4 v = *(const float4*)&Wg2[o * 64 + f4c * 4];
    *(uint2*)&lds[4096 + o * 64 + ((f4c >> 1) ^ (o & 7)) * 8 + (f4c & 1) * 4] =
        make_uint2(pk2bf(v.x, v.y), pk2bf(v.z, v.w));
  }
  __syncthreads();
  f32x4 acc[4] = {};
#pragma unroll
  for (int cs = 0; cs < 2; ++cs) {
    int hrow = w * 16 + li;
    short8 bfr = *(const short8*)&lds[hrow * 64 + ((cs * 4 + q) ^ (hrow & 7)) * 8];
#pragma unroll
    for (int mt = 0; mt < 4; ++mt) {
      int orow = mt * 16 + li;
      short8 af =
          *(const short8*)&lds[4096 + orow * 64 + ((cs * 4 + q) ^ (orow & 7)) * 8];
      acc[mt] = mfma16(af, bfr, acc[mt]);
    }
  }
  float s1 = 0.f, s2 = 0.f;
  unsigned short* zb = Zb + (size_t)(b * Cn + g * 64) * Nn;
#pragma unroll
  for (int mt = 0; mt < 4; ++mt)
#pragma unroll
    for (int r = 0; r < 4; ++r) {
      float v = acc[mt][r];
      s1 += v; s2 += v * v;
      zb[(size_t)(mt * 16 + q * 4 + r) * Nn + i0 + w * 16 + li] = f2bf(v);
    }
#pragma unroll
  for (int off = 32; off; off >>= 1) {
    s1 += __shfl_xor(s1, off);
    s2 += __shfl_xor(s2, off);
  }
  if (lane == 0) { red[w * 2] = s1; red[w * 2 + 1] = s2; }
  __syncthreads();
  if (t == 0) {
    float a1 = red[0] + red[2] + red[4] + red[6];
    float a2 = red[1] + red[3] + red[5] + red[7];
    atomicAdd(&SUMS[bg * 32], a1);
    atomicAdd(&SUMS[bg * 32 + 1], a2);
  }
}

// ---------------- K5: GroupNorm + affine + residual (padded SUMS) -------------
__global__ __launch_bounds__(256) void k_norm(
    const unsigned short* __restrict__ Zb, const float* __restrict__ x,
    const float* __restrict__ gamma, const float* __restrict__ beta,
    const float* __restrict__ SUMS, float* __restrict__ out) {
  int idx = blockIdx.x * 256 + threadIdx.x;
  size_t f = (size_t)idx * 4;
  int c = (int)((f >> 11) & (Cn - 1));
  int b = (int)(f >> 19);
  int bg = b * 4 + (c >> 6);
  const float inv = 1.f / 131072.f;
  float mean = SUMS[bg * 32] * inv;
  float var = SUMS[bg * 32 + 1] * inv - mean * mean;
  float rstd = rsqrtf(var + EPSf);
  float ga = gamma[c] * rstd;
  float be = beta[c] - mean * ga;
  uint2 u = *(const uint2*)&Zb[f];
  float4 xv = *(const float4*)(x + f);
  float4 o;
  o.x = bf2f(u.x & 0xffffu) * ga + be + xv.x;
  o.y = bf2f(u.x >> 16) * ga + be + xv.y;
  o.z = bf2f(u.y & 0xffffu) * ga + be + xv.z;
  o.w = bf2f(u.y >> 16) * ga + be + xv.w;
  *(float4*)(out + f) = o;
}

extern "C" void kernel_launch(void* const* d_in, const int* in_sizes, int n_in,
                              void* d_out, int out_size, void* d_ws, size_t ws_size,
                              hipStream_t stream) {
  (void)in_sizes; (void)n_in; (void)out_size; (void)ws_size;
  const float* x = (const float*)d_in[0];
  const float* y = (const float*)d_in[1];
  const float* Wt = (const float*)d_in[2];
  const float* Wp = (const float*)d_in[3];
  const float* Wg = (const float*)d_in[4];
  const float* Wz = (const float*)d_in[5];
  const float* gamma = (const float*)d_in[6];
  const float* beta = (const float*)d_in[7];
  float* out = (float*)d_out;
  char* ws = (char*)d_ws;
  unsigned short* Pq = (unsigned short*)(ws + 0);
  unsigned short* Tv = (unsigned short*)(ws + 4194304);
  unsigned short* Gt = (unsigned short*)(ws + 8388608);
  unsigned short* OT = (unsigned short*)(ws + 12582912);
  unsigned short* Zb = (unsigned short*)(ws + 16777216);
  float* SUMS = (float*)(ws + 20971520);  // 16 bg x 32 f32 (128B slots)

  k_mix<<<dim3(32, 12), 256, 0, stream>>>(x, y, Wp, Wt, Wg, Pq, Tv, Gt, SUMS);
  k_attn<<<512, 256, 0, stream>>>(Pq, Tv, Gt, OT);
  k_zconv<<<dim3(32, 16), 256, 0, stream>>>(Wz, OT, Zb, SUMS);
  k_norm<<<2048, 256, 0, stream>>>(Zb, x, gamma, beta, SUMS, out);
}

// Round 17
// 58.384 us; speedup vs baseline: 1.7216x; 1.0188x over previous
//
#include <hip/hip_runtime.h>

typedef __attribute__((ext_vector_type(8))) short short8;
typedef __bf16 bf16x8 __attribute__((ext_vector_type(8)));
typedef __attribute__((ext_vector_type(4))) float f32x4;

static constexpr int Cn = 256, Nn = 2048;
static constexpr float EPSf = 1e-5f;
static constexpr float LOG2E = 1.44269504088896f;

#define DEV __device__ __forceinline__

DEV unsigned short f2bf(float f) { return __builtin_bit_cast(unsigned short, (__bf16)f); }
DEV float bf2f(unsigned u16) { return __builtin_bit_cast(float, u16 << 16); }
DEV unsigned pk2bf(float a, float b) {
  return (unsigned)f2bf(a) | ((unsigned)f2bf(b) << 16);
}
DEV f32x4 mfma16(short8 a, short8 b, f32x4 c) {
  return __builtin_amdgcn_mfma_f32_16x16x32_bf16(
      __builtin_bit_cast(bf16x8, a), __builtin_bit_cast(bf16x8, b), c, 0, 0, 0);
}
DEV short8 ld8(const unsigned short* p) { return *(const short8*)p; }

// ---------------- K1: fused convert+transpose+channel-mix GEMMs (r16) ---------
__global__ __launch_bounds__(256) void k_mix(
    const float* __restrict__ x, const float* __restrict__ y,
    const float* __restrict__ Wp, const float* __restrict__ Wt,
    const float* __restrict__ Wg, unsigned short* __restrict__ P,
    unsigned short* __restrict__ T, unsigned short* __restrict__ Gt,
    float* __restrict__ SUMS) {
  __shared__ __align__(16) unsigned short lds[12800];  // A[256][40] | B[64][40]

  int t = threadIdx.x, lane = t & 63, w = t >> 6;
  int q = lane >> 4, li = lane & 15;
  int zb = blockIdx.y, b = zb & 3, op = zb >> 2;
  const float* in = (op == 0 ? x : y) + (size_t)b * Cn * Nn;
  const float* W = (op == 0 ? Wp : (op == 1 ? Wt : Wg));
  int h0 = blockIdx.x * 64;
  if (blockIdx.x == 0 && zb == 0) {  // zero padded SUMS: 16 bg x 32 floats
    SUMS[t] = 0.f;
    SUMS[256 + t] = 0.f;
  }

  int arow = t >> 3, ac4 = t & 7;   // A: 32 rows x 8 f4-cols, x8 row-groups
  int bcp = t >> 4, bh4 = t & 15;   // B: c-pair, h-quad
  float4 wv[8], bv0, bv1;
#pragma unroll
  for (int i2 = 0; i2 < 8; ++i2)
    wv[i2] = *(const float4*)&W[(size_t)(i2 * 32 + arow) * 256 + ac4 * 4];
  bv0 = *(const float4*)&in[(size_t)(2 * bcp) * Nn + h0 + bh4 * 4];
  bv1 = *(const float4*)&in[(size_t)(2 * bcp + 1) * Nn + h0 + bh4 * 4];

  unsigned* bdst = (unsigned*)&lds[10240];  // dword view: [h][c/2], 20 dw/row
  f32x4 acc[4][4] = {};
  for (int kk = 0; kk < 8; ++kk) {
    __syncthreads();
#pragma unroll
    for (int i2 = 0; i2 < 8; ++i2)
      *(uint2*)&lds[(i2 * 32 + arow) * 40 + ac4 * 4] =
          make_uint2(pk2bf(wv[i2].x, wv[i2].y), pk2bf(wv[i2].z, wv[i2].w));
    {
      int hL = bh4 * 4;
      bdst[(hL + 0) * 20 + bcp] = pk2bf(bv0.x, bv1.x);
      bdst[(hL + 1) * 20 + bcp] = pk2bf(bv0.y, bv1.y);
      bdst[(hL + 2) * 20 + bcp] = pk2bf(bv0.z, bv1.z);
      bdst[(hL + 3) * 20 + bcp] = pk2bf(bv0.w, bv1.w);
    }
    if (kk < 7) {
      int k1 = (kk + 1) * 32;
#pragma unroll
      for (int i2 = 0; i2 < 8; ++i2)
        wv[i2] = *(const float4*)&W[(size_t)(i2 * 32 + arow) * 256 + k1 + ac4 * 4];
      bv0 = *(const float4*)&in[(size_t)(k1 + 2 * bcp) * Nn + h0 + bh4 * 4];
      bv1 = *(const float4*)&in[(size_t)(k1 + 2 * bcp + 1) * Nn + h0 + bh4 * 4];
    }
    __syncthreads();
    int pw = w * 64;
    short8 af[4];
#pragma unroll
    for (int mt = 0; mt < 4; ++mt)
      af[mt] = *(const short8*)&lds[(pw + mt * 16 + li) * 40 + q * 8];
#pragma unroll
    for (int nt = 0; nt < 4; ++nt) {
      short8 bfr = *(const short8*)&lds[10240 + (nt * 16 + li) * 40 + q * 8];
#pragma unroll
      for (int mt = 0; mt < 4; ++mt) acc[mt][nt] = mfma16(af[mt], bfr, acc[mt][nt]);
    }
  }
  int pw = w * 64;
  if (op < 2) {
    unsigned short* dst = (op == 0 ? P : T) + (size_t)b * Cn * Nn;
#pragma unroll
    for (int mt = 0; mt < 4; ++mt)
#pragma unroll
      for (int nt = 0; nt < 4; ++nt)
#pragma unroll
        for (int r = 0; r < 4; ++r)
          dst[(size_t)(pw + mt * 16 + q * 4 + r) * Nn + h0 + nt * 16 + li] =
              f2bf(acc[mt][nt][r]);
  } else {
#pragma unroll
    for (int mt = 0; mt < 4; ++mt)
#pragma unroll
      for (int nt = 0; nt < 4; ++nt)
#pragma unroll
        for (int r = 0; r < 4; ++r) {
          int c = pw + mt * 16 + q * 4 + r;
          int h = h0 + nt * 16 + li;
          Gt[(((size_t)(b * 4 + (c >> 6)) * Nn + h) << 6) + (c & 63)] =
              f2bf(acc[mt][nt][r] * LOG2E);
        }
  }
}

// ---------------- K3: attention, j-split + LOCAL normalization ----------------
// 1024 blocks = 4/CU (16 waves/CU). Each block: 64 q-rows x HALF the j-range,
// r11-verbatim compute/stage. Epilogue: normalize by the block's OWN rs (r11
// lines, values O(1) -> bf16-safe) and store m_half + f32 rs_half. k_zconv
// merges with flash-combine weights. Avoids the r9/r12 failure (bf16 of large
// unnormalized partials amplified ~500x by GroupNorm's rstd).
__global__ __launch_bounds__(256) void k_attn(
    const unsigned short* __restrict__ Pq, const unsigned short* __restrict__ Tv,
    const unsigned short* __restrict__ Gt, unsigned short* __restrict__ PO0,
    unsigned short* __restrict__ PO1, float* __restrict__ RS) {
  __shared__ __align__(16) unsigned short lds[16384];  // K dbuf 2x8KB | V dbuf 2x8KB

  int t = threadIdx.x, lane = t & 63, w = t >> 6;
  int q = lane >> 4, li = lane & 15;
  int bid = blockIdx.x;
  int xcd = bid & 7, slot = bid >> 3;        // 128 slots per XCD
  int bg = xcd * 2 + (slot >> 6);            // 2 heads per XCD (L2-resident)
  int rem = slot & 63;
  int half = rem >> 5;                       // j-half
  int i0 = (rem & 31) * 64;
  int jbase = half * 1024;
  int b = bg >> 2, g = bg & 3;
  const unsigned short* Q = Pq + (size_t)(b * Cn + g * 64) * Nn;
  const unsigned short* V = Tv + (size_t)(b * Cn + g * 64) * Nn;
  const unsigned short* Kk = Gt + (size_t)bg * Nn * 64;

  int iw = i0 + w * 16;  // this wave's 16 q-rows
  short8 qf[2];
#pragma unroll
  for (int cs = 0; cs < 2; ++cs) {
    short8 v;
#pragma unroll
    for (int e = 0; e < 8; ++e)
      v[e] = (short)Q[(size_t)(cs * 32 + q * 8 + e) * Nn + iw + li];
    qf[cs] = v;
  }
  f32x4 O[4] = {};
  float rs = 0.f;

  // ---- hoisted LDS addresses (ushort units) ----
  int swz = li & 7;
  int rb0 = li * 64 + ((q ^ swz) << 3);
  int rb1 = li * 64 + (((4 + q) ^ swz) << 3);
  int srow = t >> 2, sq = t & 3;
  int wk0 = srow * 64 + ((sq ^ (srow & 7)) << 3);
  int wk1 = srow * 64 + (((sq + 4) ^ (srow & 7)) << 3);

  // ---- running global staging pointers (advance by const per tile) ----
  const unsigned short* kp0 = Kk + (size_t)(jbase + srow) * 64 + sq * 8;
  const unsigned short* kp1 = kp0 + 32;
  const unsigned short* vp0 = V + (size_t)srow * Nn + jbase + sq * 8;
  const unsigned short* vp1 = vp0 + 32;

  short8 kst[2], vst[2];
  kst[0] = ld8(kp0); kst[1] = ld8(kp1);
  vst[0] = ld8(vp0); vst[1] = ld8(vp1);
  kp0 += 4096; kp1 += 4096; vp0 += 64; vp1 += 64;

  auto load_next = [&]() {
    kst[0] = ld8(kp0); kst[1] = ld8(kp1);
    vst[0] = ld8(vp0); vst[1] = ld8(vp1);
    kp0 += 4096; kp1 += 4096; vp0 += 64; vp1 += 64;
  };

  auto stage = [&](int KB) {  // KB literal: 0 or 4096
    *(short8*)&lds[KB + wk0] = kst[0];
    *(short8*)&lds[KB + wk1] = kst[1];
    *(short8*)&lds[KB + 8192 + wk0] = vst[0];
    *(short8*)&lds[KB + 8192 + wk1] = vst[1];
  };

  auto compute = [&](int KB) {  // KB literal: 0 or 4096
    f32x4 F[4] = {};
#pragma unroll
    for (int jt = 0; jt < 4; ++jt) {
      short8 k0 = *(const short8*)&lds[KB + jt * 1024 + rb0];
      short8 k1 = *(const short8*)&lds[KB + jt * 1024 + rb1];
      F[jt] = mfma16(k0, qf[0], F[jt]);
      F[jt] = mfma16(k1, qf[1], F[jt]);
    }
    unsigned pa[4], pb[4];
#pragma unroll
    for (int jt = 0; jt < 4; ++jt) {
      float e0 = __builtin_amdgcn_exp2f(F[jt][0]);
      float e1 = __builtin_amdgcn_exp2f(F[jt][1]);
      float e2 = __builtin_amdgcn_exp2f(F[jt][2]);
      float e3 = __builtin_amdgcn_exp2f(F[jt][3]);
      rs += (e0 + e1) + (e2 + e3);
      pa[jt] = pk2bf(e0, e1);
      pb[jt] = pk2bf(e2, e3);
    }
#pragma unroll
    for (int cs = 0; cs < 2; ++cs) {
      unsigned a0 = pa[2 * cs], a1 = pa[2 * cs + 1];
      unsigned b0 = pb[2 * cs], b1 = pb[2 * cs + 1];
      asm("v_permlane32_swap_b32 %0, %1" : "+v"(a0), "+v"(a1));
      asm("v_permlane16_swap_b32 %0, %1" : "+v"(a0), "+v"(a1));
      asm("v_permlane32_swap_b32 %0, %1" : "+v"(b0), "+v"(b1));
      asm("v_permlane16_swap_b32 %0, %1" : "+v"(b0), "+v"(b1));
      int4 fi = make_int4((int)a0, (int)b0, (int)a1, (int)b1);
      short8 pf = __builtin_bit_cast(short8, fi);
      int rbv = cs ? rb1 : rb0;
#pragma unroll
      for (int ct = 0; ct < 4; ++ct) {
        short8 vf = *(const short8*)&lds[KB + 8192 + ct * 1024 + rbv];
        O[ct] = mfma16(pf, vf, O[ct]);
      }
    }
  };

  for (int tp = 0; tp < 8; ++tp) {
    __syncthreads();
    stage(0);
    load_next();
    if (tp > 0) compute(4096);
    __syncthreads();
    stage(4096);
    if (tp < 7) load_next();
    compute(0);
  }
  __syncthreads();
  compute(4096);  // tile 15 lives in buf 1

  // epilogue: local-rs normalize (r11 verbatim) + rs_half store
  rs += __shfl_xor(rs, 16);
  rs += __shfl_xor(rs, 32);
  if (q == 0) RS[(size_t)(half * 16 + bg) * Nn + iw + li] = rs;
  float r0 = 1.f / __shfl(rs, q * 4 + 0);
  float r1 = 1.f / __shfl(rs, q * 4 + 1);
  float r2 = 1.f / __shfl(rs, q * 4 + 2);
  float r3 = 1.f / __shfl(rs, q * 4 + 3);
  unsigned short* PO = (half ? PO1 : PO0) + (size_t)bg * Nn * 64;
#pragma unroll
  for (int ct = 0; ct < 4; ++ct) {
    PO[(size_t)(iw + q * 4 + 0) * 64 + ct * 16 + li] = f2bf(O[ct][0] * r0);
    PO[(size_t)(iw + q * 4 + 1) * 64 + ct * 16 + li] = f2bf(O[ct][1] * r1);
    PO[(size_t)(iw + q * 4 + 2) * 64 + ct * 16 + li] = f2bf(O[ct][2] * r2);
    PO[(size_t)(iw + q * 4 + 3) * 64 + ct * 16 + li] = f2bf(O[ct][3] * r3);
  }
}

// ---------------- K4: flash-combine merge + grouped conv + sum/sumsq ----------
// r16 structure (64-row blocks, block-reduced atomics into padded SUMS).
// Staging merges halves: m = m0*w0 + m1*w1, w_h = rs_h/(rs0+rs1).
__global__ __launch_bounds__(256) void k_zconv(
    const float* __restrict__ Wz, const unsigned short* __restrict__ PO0,
    const unsigned short* __restrict__ PO1, const float* __restrict__ RS,
    unsigned short* __restrict__ Zb, float* __restrict__ SUMS) {
  __shared__ __align__(16) unsigned short lds[8192];  // m[64][64] | Wzs[64][64]
  __shared__ float red[8];
  int t = threadIdx.x, lane = t & 63, w = t >> 6;
  int q = lane >> 4, li = lane & 15;
  int bg = blockIdx.y, b = bg >> 2, g = bg & 3;
  int i0 = blockIdx.x * 64;
  const unsigned short* po0 = PO0 + ((size_t)bg * Nn + i0) * 64;
  const unsigned short* po1 = PO1 + ((size_t)bg * Nn + i0) * 64;
  const float* rs0p = RS + (size_t)bg * Nn + i0;
  const float* rs1p = RS + (size_t)(16 + bg) * Nn + i0;
#pragma unroll
  for (int p = 0; p < 2; ++p) {
    int chunk = p * 256 + t;
    int row = chunk >> 3, sl = chunk & 7;
    short8 a = ld8(po0 + row * 64 + sl * 8);
    short8 bb = ld8(po1 + row * 64 + sl * 8);
    float ra = rs0p[row], rb = rs1p[row];
    float inv = 1.f / (ra + rb);
    float w0 = ra * inv, w1 = rb * inv;
    short8 m;
#pragma unroll
    for (int e = 0; e < 8; ++e)
      m[e] = (short)f2bf(bf2f((unsigned short)a[e]) * w0 +
                         bf2f((unsigned short)bb[e]) * w1);
    *(short8*)&lds[row * 64 + (sl ^ (row & 7)) * 8] = m;
  }
  const float* Wg2 = Wz + g * 64 * 64;
#pragma unroll
  for (int p = 0; p < 4; ++p) {
    int o = p * 16 + (t >> 4), f4c = t & 15;
    float4 v = *(const float4*)&Wg2[o * 64 + f4c * 4];
    *(uint2*)&lds[4096 + o * 64 + ((f4c >> 1) ^ (o & 7)) * 8 + (f4c & 1) * 4] =
        make_uint2(pk2bf(v.x, v.y), pk2bf(v.z, v.w));
  }
  __syncthreads();
  f32x4 acc[4] = {};
#pragma unroll
  for (int cs = 0; cs < 2; ++cs) {
    int hrow = w * 16 + li;
    short8 bfr = *(const short8*)&lds[hrow * 64 + ((cs * 4 + q) ^ (hrow & 7)) * 8];
#pragma unroll
    for (int mt = 0; mt < 4; ++mt) {
      int orow = mt * 16 + li;
      short8 af =
          *(const short8*)&lds[4096 + orow * 64 + ((cs * 4 + q) ^ (orow & 7)) * 8];
      acc[mt] = mfma16(af, bfr, acc[mt]);
    }
  }
  float s1 = 0.f, s2 = 0.f;
  unsigned short* zb = Zb + (size_t)(b * Cn + g * 64) * Nn;
#pragma unroll
  for (int mt = 0; mt < 4; ++mt)
#pragma unroll
    for (int r = 0; r < 4; ++r) {
      float v = acc[mt][r];
      s1 += v; s2 += v * v;
      zb[(size_t)(mt * 16 + q * 4 + r) * Nn + i0 + w * 16 + li] = f2bf(v);
    }
#pragma unroll
  for (int off = 32; off; off >>= 1) {
    s1 += __shfl_xor(s1, off);
    s2 += __shfl_xor(s2, off);
  }
  if (lane == 0) { red[w * 2] = s1; red[w * 2 + 1] = s2; }
  __syncthreads();
  if (t == 0) {
    float a1 = red[0] + red[2] + red[4] + red[6];
    float a2 = red[1] + red[3] + red[5] + red[7];
    atomicAdd(&SUMS[bg * 32], a1);
    atomicAdd(&SUMS[bg * 32 + 1], a2);
  }
}

// ---------------- K5: GroupNorm + affine + residual (padded SUMS) -------------
__global__ __launch_bounds__(256) void k_norm(
    const unsigned short* __restrict__ Zb, const float* __restrict__ x,
    const float* __restrict__ gamma, const float* __restrict__ beta,
    const float* __restrict__ SUMS, float* __restrict__ out) {
  int idx = blockIdx.x * 256 + threadIdx.x;
  size_t f = (size_t)idx * 4;
  int c = (int)((f >> 11) & (Cn - 1));
  int b = (int)(f >> 19);
  int bg = b * 4 + (c >> 6);
  const float inv = 1.f / 131072.f;
  float mean = SUMS[bg * 32] * inv;
  float var = SUMS[bg * 32 + 1] * inv - mean * mean;
  float rstd = rsqrtf(var + EPSf);
  float ga = gamma[c] * rstd;
  float be = beta[c] - mean * ga;
  uint2 u = *(const uint2*)&Zb[f];
  float4 xv = *(const float4*)(x + f);
  float4 o;
  o.x = bf2f(u.x & 0xffffu) * ga + be + xv.x;
  o.y = bf2f(u.x >> 16) * ga + be + xv.y;
  o.z = bf2f(u.y & 0xffffu) * ga + be + xv.z;
  o.w = bf2f(u.y >> 16) * ga + be + xv.w;
  *(float4*)(out + f) = o;
}

extern "C" void kernel_launch(void* const* d_in, const int* in_sizes, int n_in,
                              void* d_out, int out_size, void* d_ws, size_t ws_size,
                              hipStream_t stream) {
  (void)in_sizes; (void)n_in; (void)out_size; (void)ws_size;
  const float* x = (const float*)d_in[0];
  const float* y = (const float*)d_in[1];
  const float* Wt = (const float*)d_in[2];
  const float* Wp = (const float*)d_in[3];
  const float* Wg = (const float*)d_in[4];
  const float* Wz = (const float*)d_in[5];
  const float* gamma = (const float*)d_in[6];
  const float* beta = (const float*)d_in[7];
  float* out = (float*)d_out;
  char* ws = (char*)d_ws;
  unsigned short* Pq  = (unsigned short*)(ws + 0);
  unsigned short* Tv  = (unsigned short*)(ws + 4194304);
  unsigned short* Gt  = (unsigned short*)(ws + 8388608);
  unsigned short* PO0 = (unsigned short*)(ws + 12582912);
  unsigned short* PO1 = (unsigned short*)(ws + 16777216);
  float* RS   = (float*)(ws + 20971520);   // [2][16][2048] f32 = 256KB
  float* SUMS = (float*)(ws + 21233664);   // 16 bg x 32 f32 (128B slots)
  unsigned short* Zb = Pq;  // Pq dead after k_attn

  k_mix<<<dim3(32, 12), 256, 0, stream>>>(x, y, Wp, Wt, Wg, Pq, Tv, Gt, SUMS);
  k_attn<<<1024, 256, 0, stream>>>(Pq, Tv, Gt, PO0, PO1, RS);
  k_zconv<<<dim3(32, 16), 256, 0, stream>>>(Wz, PO0, PO1, RS, Zb, SUMS);
  k_norm<<<2048, 256, 0, stream>>>(Zb, x, gamma, beta, SUMS, out);
}